// Round 4
// baseline (211.380 us; speedup 1.0000x reference)
//
#include <hip/hip_runtime.h>
#include <hip/hip_bf16.h>

// GraphConvNet: x:[8,2048,32] f32, A0/A1/A2:[8,2048,2048] f32 row-normalized,
// W:[64,224], b/gamma/beta:[64].
// nconv: out[n,w,l] = sum_v A[n,v,w] * x[n,v,l]
// feat = concat([x, x1_0, x2_0, x1_1, x2_1, x1_2, x2_2])  (224 ch)
// h = feat @ W^T + b ; BN over (n,v) per channel; out f32 [8,2048,64]

#define V    2048
#define NB   8
#define CIN  32
#define COUT 64
#define CTOT 224

typedef __attribute__((ext_vector_type(8))) short bf16x8;
typedef __attribute__((ext_vector_type(16))) float f32x16;

static __device__ __forceinline__ short f2bf(float f) {
  __hip_bfloat16 h = __float2bfloat16(f);  // RNE
  return *reinterpret_cast<short*>(&h);
}

// ---------------------------------------------------------------------------
// nconv via MFMA 32x32x16 bf16, register-ring pipelined, no LDS in main loop.
// Block: 4 waves, each owns a K-quarter (512 v) of one (n, 32-w strip).
// Register ring depth 4 (named slots a0..a3/x0..x3, static indexing only).
// Per k-step: 16 global_load_dword (each = 2 x 128B rows, coalesced),
// s_waitcnt vmcnt(48) => 3 chunks in flight, cvt to bf16, one MFMA.
// k-slot map (same bijection both operands => correct): v = v0 + 8g + j.
// ---------------------------------------------------------------------------
__global__ __launch_bounds__(256) void nconv_mfma_kernel(
    const float* __restrict__ Adj, const float* __restrict__ Xin,
    float* __restrict__ Xout) {
  __shared__ float Lred[4][32][33];  // cross-wave reduce only (~17 KB)

  const int bid  = blockIdx.x;    // 512 blocks
  const int n    = bid >> 6;
  const int ws   = (bid & 63) * 32;
  const int t    = threadIdx.x;
  const int q    = t >> 6;        // wave id = K quarter
  const int lane = t & 63;
  const int g    = lane >> 5;
  const int mn   = lane & 31;     // m (=l) for A-op, n (=w) for B-op

  // per-lane bases; chunk c adds c*16 rows
  const float* __restrict__ Ap =
      Adj + (size_t)n * V * V + (size_t)(q * 512 + 8 * g) * V + ws + mn;
  const float* __restrict__ Xp =
      Xin + (size_t)n * V * CIN + (q * 512 + 8 * g) * CIN + mn;

  float a0[8], a1[8], a2[8], a3[8];
  float x0[8], x1[8], x2[8], x3[8];

#define STAGE(S, C)                                                  \
  do {                                                               \
    const float* __restrict__ ap_ = Ap + (size_t)(C) * (16 * V);     \
    const float* __restrict__ xp_ = Xp + (C) * (16 * CIN);           \
    _Pragma("unroll") for (int j = 0; j < 8; ++j) {                  \
      a##S[j] = ap_[(size_t)j * V];                                  \
      x##S[j] = xp_[j * CIN];                                        \
    }                                                                \
  } while (0)

#define WAITV(N)                                         \
  do {                                                   \
    asm volatile("s_waitcnt vmcnt(" #N ")" ::: "memory");\
    __builtin_amdgcn_sched_barrier(0);                   \
  } while (0)

  f32x16 acc;
#pragma unroll
  for (int r = 0; r < 16; ++r) acc[r] = 0.f;

#define COMPUTE(S)                                                   \
  do {                                                               \
    bf16x8 aop_, bop_;                                               \
    _Pragma("unroll") for (int j = 0; j < 8; ++j) {                  \
      aop_[j] = f2bf(x##S[j]); /* X^T is the A operand */            \
      bop_[j] = f2bf(a##S[j]); /* Adj   is the B operand */          \
    }                                                                \
    acc = __builtin_amdgcn_mfma_f32_32x32x16_bf16(aop_, bop_, acc,   \
                                                  0, 0, 0);          \
  } while (0)

  STAGE(0, 0);
  STAGE(1, 1);
  STAGE(2, 2);
#pragma unroll 1
  for (int it = 0; it < 7; ++it) {  // computes chunks 0..27, stages 3..30
    const int kb = it * 4;
    STAGE(3, kb + 3); WAITV(48); COMPUTE(0);
    STAGE(0, kb + 4); WAITV(48); COMPUTE(1);
    STAGE(1, kb + 5); WAITV(48); COMPUTE(2);
    STAGE(2, kb + 6); WAITV(48); COMPUTE(3);
  }
  STAGE(3, 31); WAITV(48); COMPUTE(0);  // chunk 28
  WAITV(32); COMPUTE(1);                // chunk 29
  WAITV(16); COMPUTE(2);                // chunk 30
  WAITV(0);  COMPUTE(3);                // chunk 31

#undef STAGE
#undef WAITV
#undef COMPUTE

  // ---- cross-wave K reduce ----
#pragma unroll
  for (int r = 0; r < 16; ++r) {
    // C^T[l][w]: row l = (r&3)+8*(r>>2)+4*g, col w = mn
    Lred[q][(r & 3) + 8 * (r >> 2) + 4 * g][mn] = acc[r];
  }
  __syncthreads();
  const int w  = t >> 3;
  const int l4 = t & 7;
  float4 o;
  float* op = &o.x;
#pragma unroll
  for (int i = 0; i < 4; ++i) {
    op[i] = Lred[0][l4 * 4 + i][w] + Lred[1][l4 * 4 + i][w] +
            Lred[2][l4 * 4 + i][w] + Lred[3][l4 * 4 + i][w];
  }
  *(float4*)(Xout + ((size_t)n * V + ws + w) * CIN + l4 * 4) = o;
}

// ---------------------------------------------------------------------------
// conv 1x1 + bias + BN batch-stats partials (unchanged, passing).
// ---------------------------------------------------------------------------
__global__ __launch_bounds__(256) void conv_bn_stats_kernel(
    const float* __restrict__ W, const float* __restrict__ bias,
    const float* __restrict__ p0, const float* __restrict__ p1,
    const float* __restrict__ p2, const float* __restrict__ p3,
    const float* __restrict__ p4, const float* __restrict__ p5,
    const float* __restrict__ p6, float* __restrict__ hout,
    float* __restrict__ stats) {
  __shared__ float Wl[COUT * CTOT];
  __shared__ float Fl[64 * CTOT];
  const int t = threadIdx.x;
  const int R0 = blockIdx.x * 64;

#pragma unroll
  for (int s = 0; s < 14; ++s) {
    int fl = t + s * 256;
    int o = fl / 56, c4 = fl % 56;
    float4 wv = *(const float4*)(W + o * CTOT + c4 * 4);
    int c = c4 * 4;
    int csw = c ^ (((o >> 2) & 7) << 2);
    *(float4*)&Wl[o * CTOT + csw] = wv;
  }
  const float* parts[7] = {p0, p1, p2, p3, p4, p5, p6};
#pragma unroll
  for (int p = 0; p < 7; ++p) {
    const float* __restrict__ src = parts[p] + (size_t)R0 * CIN;
#pragma unroll
    for (int s = 0; s < 2; ++s) {
      int fl = t + s * 256;
      int r = fl >> 3, c4 = fl & 7;
      float4 v = *(const float4*)(src + r * CIN + c4 * 4);
      int c = p * 32 + c4 * 4;
      int csw = c ^ (((r >> 2) & 7) << 2);
      *(float4*)&Fl[r * CTOT + csw] = v;
    }
  }
  __syncthreads();

  const int rg = t & 15, og = t >> 4;
  const int r0 = rg * 4, o0 = og * 4;
  float acc[4][4];
#pragma unroll
  for (int i = 0; i < 4; ++i)
#pragma unroll
    for (int j = 0; j < 4; ++j) acc[i][j] = bias[o0 + j];

  const int fsw = (rg & 7) << 2;
  const int wsw = (og & 7) << 2;
  for (int cc = 0; cc < CTOT; cc += 4) {
    float4 f[4], w[4];
#pragma unroll
    for (int i = 0; i < 4; ++i)
      f[i] = *(const float4*)&Fl[(r0 + i) * CTOT + (cc ^ fsw)];
#pragma unroll
    for (int j = 0; j < 4; ++j)
      w[j] = *(const float4*)&Wl[(o0 + j) * CTOT + (cc ^ wsw)];
#pragma unroll
    for (int i = 0; i < 4; ++i)
#pragma unroll
      for (int j = 0; j < 4; ++j)
        acc[i][j] += f[i].x * w[j].x + f[i].y * w[j].y + f[i].z * w[j].z +
                     f[i].w * w[j].w;
  }

#pragma unroll
  for (int i = 0; i < 4; ++i) {
    *(float4*)(hout + (size_t)(R0 + r0 + i) * COUT + o0) =
        make_float4(acc[i][0], acc[i][1], acc[i][2], acc[i][3]);
  }

  __syncthreads();
  float* red = Fl;
#pragma unroll
  for (int j = 0; j < 4; ++j) {
    float s = acc[0][j] + acc[1][j] + acc[2][j] + acc[3][j];
    float qq = acc[0][j] * acc[0][j] + acc[1][j] * acc[1][j] +
               acc[2][j] * acc[2][j] + acc[3][j] * acc[3][j];
    red[(o0 + j) * 16 + rg] = s;
    red[1024 + (o0 + j) * 16 + rg] = qq;
  }
  __syncthreads();
  if (t < 128) {
    int o = t & 63, which = t >> 6;
    const float* b = red + which * 1024 + o * 16;
    float v = 0.f;
#pragma unroll
    for (int k = 0; k < 16; ++k) v += b[k];
    atomicAdd(stats + which * COUT + o, v);
  }
}

// ---------------------------------------------------------------------------
__global__ __launch_bounds__(256) void bn_apply_kernel(
    float* __restrict__ hout, const float* __restrict__ stats,
    const float* __restrict__ gamma, const float* __restrict__ beta) {
  const int i4 = blockIdx.x * 256 + threadIdx.x;
  const int oi = i4 & 15;
  float4 h = ((const float4*)hout)[i4];
  const float4 s = ((const float4*)stats)[oi];
  const float4 q = ((const float4*)(stats + COUT))[oi];
  const float4 g = ((const float4*)gamma)[oi];
  const float4 bb = ((const float4*)beta)[oi];
  const float inv = 1.f / 16384.f;
  float m, vv, rs;
  m = s.x * inv; vv = q.x * inv - m * m; rs = rsqrtf(vv + 1e-5f);
  h.x = (h.x - m) * rs * g.x + bb.x;
  m = s.y * inv; vv = q.y * inv - m * m; rs = rsqrtf(vv + 1e-5f);
  h.y = (h.y - m) * rs * g.y + bb.y;
  m = s.z * inv; vv = q.z * inv - m * m; rs = rsqrtf(vv + 1e-5f);
  h.z = (h.z - m) * rs * g.z + bb.z;
  m = s.w * inv; vv = q.w * inv - m * m; rs = rsqrtf(vv + 1e-5f);
  h.w = (h.w - m) * rs * g.w + bb.w;
  ((float4*)hout)[i4] = h;
}

// ---------------------------------------------------------------------------
extern "C" void kernel_launch(void* const* d_in, const int* in_sizes, int n_in,
                              void* d_out, int out_size, void* d_ws,
                              size_t ws_size, hipStream_t stream) {
  const float* x     = (const float*)d_in[0];
  const float* A0    = (const float*)d_in[1];
  const float* A1    = (const float*)d_in[2];
  const float* A2    = (const float*)d_in[3];
  const float* W     = (const float*)d_in[4];
  const float* b     = (const float*)d_in[5];
  const float* gamma = (const float*)d_in[6];
  const float* beta  = (const float*)d_in[7];
  float* out = (float*)d_out;

  char* ws = (char*)d_ws;
  float* stats = (float*)ws;
  const size_t BUF = (size_t)NB * V * CIN;  // 524288 floats
  float* x1_0 = (float*)(ws + 4096);
  float* x2_0 = x1_0 + BUF;
  float* x1_1 = x2_0 + BUF;
  float* x2_1 = x1_1 + BUF;
  float* x1_2 = x2_1 + BUF;
  float* x2_2 = x1_2 + BUF;

  hipMemsetAsync(stats, 0, 2 * COUT * sizeof(float), stream);

  dim3 g(512), blk(256);
  // per-A pairs so hop2 re-reads A from Infinity Cache (128 MB < 256 MB L3)
  nconv_mfma_kernel<<<g, blk, 0, stream>>>(A0, x, x1_0);
  nconv_mfma_kernel<<<g, blk, 0, stream>>>(A0, x1_0, x2_0);
  nconv_mfma_kernel<<<g, blk, 0, stream>>>(A1, x, x1_1);
  nconv_mfma_kernel<<<g, blk, 0, stream>>>(A1, x1_1, x2_1);
  nconv_mfma_kernel<<<g, blk, 0, stream>>>(A2, x, x1_2);
  nconv_mfma_kernel<<<g, blk, 0, stream>>>(A2, x1_2, x2_2);

  conv_bn_stats_kernel<<<dim3(256), blk, 0, stream>>>(
      W, b, x, x1_0, x2_0, x1_1, x2_1, x1_2, x2_2, out, stats);
  bn_apply_kernel<<<dim3(1024), blk, 0, stream>>>(out, stats, gamma, beta);
}

// Round 5
// 210.118 us; speedup vs baseline: 1.0060x; 1.0060x over previous
//
#include <hip/hip_runtime.h>
#include <hip/hip_bf16.h>

// GraphConvNet: x:[8,2048,32] f32, A0/A1/A2:[8,2048,2048] f32 row-normalized,
// W:[64,224], b/gamma/beta:[64].
// nconv: out[n,w,l] = sum_v A[n,v,w] * x[n,v,l]
// feat = concat([x, x1_0, x2_0, x1_1, x2_1, x1_2, x2_2])  (224 ch)
// h = feat @ W^T + b ; BN over (n,v) per channel; out f32 [8,2048,64]
//
// Schedule (3 independent chains h1(Aj)->h2(Aj), pipelined across kernels):
//   K1 = h1(A0); K2 = h2(A0)||h1(A1); K3 = h2(A1)||h1(A2); K4 = h2(A2)
// Each h2 reads its A from Infinity Cache (134 MB resident from prev kernel)
// while the next A streams from HBM.

#define V    2048
#define NB   8
#define CIN  32
#define COUT 64
#define CTOT 224

typedef __attribute__((ext_vector_type(8))) short bf16x8;
typedef __attribute__((ext_vector_type(16))) float f32x16;

static __device__ __forceinline__ short f2bf(float f) {
  __hip_bfloat16 h = __float2bfloat16(f);  // RNE
  return *reinterpret_cast<short*>(&h);
}

// ---------------------------------------------------------------------------
// Dual-job nconv via MFMA 32x32x16 bf16, register-ring pipelined.
// grid = 512 (single job) or 1024 (two jobs, even/odd interleaved).
// Per job-block: 4 waves, each owns a K-quarter (512 v) of one (n, 32-w strip).
// Register ring depth 4 (named slots, static indexing). Per k-step: 16
// global_load_dword (each = 2 x 128B lines), s_waitcnt vmcnt(48), cvt, MFMA.
// k-slot map (same bijection both operands => correct): v = v0 + 8g + j.
// ---------------------------------------------------------------------------
__global__ __launch_bounds__(256) void nconv_mfma_dual_kernel(
    const float* __restrict__ AdjA, const float* __restrict__ XinA,
    float* __restrict__ XoutA, const float* __restrict__ AdjB,
    const float* __restrict__ XinB, float* __restrict__ XoutB) {
  __shared__ float Lred[4][32][33];  // cross-wave reduce only (~17 KB)

  const int bid  = blockIdx.x;
  int job, sub;
  if (gridDim.x > 512) {        // two jobs interleaved even/odd
    job = bid & 1;
    sub = bid >> 1;
  } else {
    job = 0;
    sub = bid;
  }
  const float* Adj  = job ? AdjB : AdjA;
  const float* Xin  = job ? XinB : XinA;
  float*       Xout = job ? XoutB : XoutA;

  const int n    = sub >> 6;
  const int ws   = (sub & 63) * 32;
  const int t    = threadIdx.x;
  const int q    = t >> 6;        // wave id = K quarter
  const int lane = t & 63;
  const int g    = lane >> 5;
  const int mn   = lane & 31;     // m (=l) for A-op, n (=w) for B-op

  // per-lane bases; chunk c adds c*16 rows
  const float* __restrict__ Ap =
      Adj + (size_t)n * V * V + (size_t)(q * 512 + 8 * g) * V + ws + mn;
  const float* __restrict__ Xp =
      Xin + (size_t)n * V * CIN + (q * 512 + 8 * g) * CIN + mn;

  float a0[8], a1[8], a2[8], a3[8];
  float x0[8], x1[8], x2[8], x3[8];

#define STAGE(S, C)                                                  \
  do {                                                               \
    const float* __restrict__ ap_ = Ap + (size_t)(C) * (16 * V);     \
    const float* __restrict__ xp_ = Xp + (C) * (16 * CIN);           \
    _Pragma("unroll") for (int j = 0; j < 8; ++j) {                  \
      a##S[j] = ap_[(size_t)j * V];                                  \
      x##S[j] = xp_[j * CIN];                                        \
    }                                                                \
  } while (0)

#define WAITV(N)                                         \
  do {                                                   \
    asm volatile("s_waitcnt vmcnt(" #N ")" ::: "memory");\
    __builtin_amdgcn_sched_barrier(0);                   \
  } while (0)

  f32x16 acc;
#pragma unroll
  for (int r = 0; r < 16; ++r) acc[r] = 0.f;

#define COMPUTE(S)                                                   \
  do {                                                               \
    bf16x8 aop_, bop_;                                               \
    _Pragma("unroll") for (int j = 0; j < 8; ++j) {                  \
      aop_[j] = f2bf(x##S[j]); /* X^T is the A operand */            \
      bop_[j] = f2bf(a##S[j]); /* Adj   is the B operand */          \
    }                                                                \
    acc = __builtin_amdgcn_mfma_f32_32x32x16_bf16(aop_, bop_, acc,   \
                                                  0, 0, 0);          \
  } while (0)

  STAGE(0, 0);
  STAGE(1, 1);
  STAGE(2, 2);
#pragma unroll 1
  for (int it = 0; it < 7; ++it) {  // computes chunks 0..27, stages 3..30
    const int kb = it * 4;
    STAGE(3, kb + 3); WAITV(48); COMPUTE(0);
    STAGE(0, kb + 4); WAITV(48); COMPUTE(1);
    STAGE(1, kb + 5); WAITV(48); COMPUTE(2);
    STAGE(2, kb + 6); WAITV(48); COMPUTE(3);
  }
  STAGE(3, 31); WAITV(48); COMPUTE(0);  // chunk 28
  WAITV(32); COMPUTE(1);                // chunk 29
  WAITV(16); COMPUTE(2);                // chunk 30
  WAITV(0);  COMPUTE(3);                // chunk 31

#undef STAGE
#undef WAITV
#undef COMPUTE

  // ---- cross-wave K reduce ----
#pragma unroll
  for (int r = 0; r < 16; ++r) {
    // C^T[l][w]: row l = (r&3)+8*(r>>2)+4*g, col w = mn
    Lred[q][(r & 3) + 8 * (r >> 2) + 4 * g][mn] = acc[r];
  }
  __syncthreads();
  const int w  = t >> 3;
  const int l4 = t & 7;
  float4 o;
  float* op = &o.x;
#pragma unroll
  for (int i = 0; i < 4; ++i) {
    op[i] = Lred[0][l4 * 4 + i][w] + Lred[1][l4 * 4 + i][w] +
            Lred[2][l4 * 4 + i][w] + Lred[3][l4 * 4 + i][w];
  }
  *(float4*)(Xout + ((size_t)n * V + ws + w) * CIN + l4 * 4) = o;
}

// ---------------------------------------------------------------------------
// conv 1x1 + bias + BN batch-stats partials (unchanged, passing).
// ---------------------------------------------------------------------------
__global__ __launch_bounds__(256) void conv_bn_stats_kernel(
    const float* __restrict__ W, const float* __restrict__ bias,
    const float* __restrict__ p0, const float* __restrict__ p1,
    const float* __restrict__ p2, const float* __restrict__ p3,
    const float* __restrict__ p4, const float* __restrict__ p5,
    const float* __restrict__ p6, float* __restrict__ hout,
    float* __restrict__ stats) {
  __shared__ float Wl[COUT * CTOT];
  __shared__ float Fl[64 * CTOT];
  const int t = threadIdx.x;
  const int R0 = blockIdx.x * 64;

#pragma unroll
  for (int s = 0; s < 14; ++s) {
    int fl = t + s * 256;
    int o = fl / 56, c4 = fl % 56;
    float4 wv = *(const float4*)(W + o * CTOT + c4 * 4);
    int c = c4 * 4;
    int csw = c ^ (((o >> 2) & 7) << 2);
    *(float4*)&Wl[o * CTOT + csw] = wv;
  }
  const float* parts[7] = {p0, p1, p2, p3, p4, p5, p6};
#pragma unroll
  for (int p = 0; p < 7; ++p) {
    const float* __restrict__ src = parts[p] + (size_t)R0 * CIN;
#pragma unroll
    for (int s = 0; s < 2; ++s) {
      int fl = t + s * 256;
      int r = fl >> 3, c4 = fl & 7;
      float4 v = *(const float4*)(src + r * CIN + c4 * 4);
      int c = p * 32 + c4 * 4;
      int csw = c ^ (((r >> 2) & 7) << 2);
      *(float4*)&Fl[r * CTOT + csw] = v;
    }
  }
  __syncthreads();

  const int rg = t & 15, og = t >> 4;
  const int r0 = rg * 4, o0 = og * 4;
  float acc[4][4];
#pragma unroll
  for (int i = 0; i < 4; ++i)
#pragma unroll
    for (int j = 0; j < 4; ++j) acc[i][j] = bias[o0 + j];

  const int fsw = (rg & 7) << 2;
  const int wsw = (og & 7) << 2;
  for (int cc = 0; cc < CTOT; cc += 4) {
    float4 f[4], w[4];
#pragma unroll
    for (int i = 0; i < 4; ++i)
      f[i] = *(const float4*)&Fl[(r0 + i) * CTOT + (cc ^ fsw)];
#pragma unroll
    for (int j = 0; j < 4; ++j)
      w[j] = *(const float4*)&Wl[(o0 + j) * CTOT + (cc ^ wsw)];
#pragma unroll
    for (int i = 0; i < 4; ++i)
#pragma unroll
      for (int j = 0; j < 4; ++j)
        acc[i][j] += f[i].x * w[j].x + f[i].y * w[j].y + f[i].z * w[j].z +
                     f[i].w * w[j].w;
  }

#pragma unroll
  for (int i = 0; i < 4; ++i) {
    *(float4*)(hout + (size_t)(R0 + r0 + i) * COUT + o0) =
        make_float4(acc[i][0], acc[i][1], acc[i][2], acc[i][3]);
  }

  __syncthreads();
  float* red = Fl;
#pragma unroll
  for (int j = 0; j < 4; ++j) {
    float s = acc[0][j] + acc[1][j] + acc[2][j] + acc[3][j];
    float qq = acc[0][j] * acc[0][j] + acc[1][j] * acc[1][j] +
               acc[2][j] * acc[2][j] + acc[3][j] * acc[3][j];
    red[(o0 + j) * 16 + rg] = s;
    red[1024 + (o0 + j) * 16 + rg] = qq;
  }
  __syncthreads();
  if (t < 128) {
    int o = t & 63, which = t >> 6;
    const float* b = red + which * 1024 + o * 16;
    float v = 0.f;
#pragma unroll
    for (int k = 0; k < 16; ++k) v += b[k];
    atomicAdd(stats + which * COUT + o, v);
  }
}

// ---------------------------------------------------------------------------
__global__ __launch_bounds__(256) void bn_apply_kernel(
    float* __restrict__ hout, const float* __restrict__ stats,
    const float* __restrict__ gamma, const float* __restrict__ beta) {
  const int i4 = blockIdx.x * 256 + threadIdx.x;
  const int oi = i4 & 15;
  float4 h = ((const float4*)hout)[i4];
  const float4 s = ((const float4*)stats)[oi];
  const float4 q = ((const float4*)(stats + COUT))[oi];
  const float4 g = ((const float4*)gamma)[oi];
  const float4 bb = ((const float4*)beta)[oi];
  const float inv = 1.f / 16384.f;
  float m, vv, rs;
  m = s.x * inv; vv = q.x * inv - m * m; rs = rsqrtf(vv + 1e-5f);
  h.x = (h.x - m) * rs * g.x + bb.x;
  m = s.y * inv; vv = q.y * inv - m * m; rs = rsqrtf(vv + 1e-5f);
  h.y = (h.y - m) * rs * g.y + bb.y;
  m = s.z * inv; vv = q.z * inv - m * m; rs = rsqrtf(vv + 1e-5f);
  h.z = (h.z - m) * rs * g.z + bb.z;
  m = s.w * inv; vv = q.w * inv - m * m; rs = rsqrtf(vv + 1e-5f);
  h.w = (h.w - m) * rs * g.w + bb.w;
  ((float4*)hout)[i4] = h;
}

// ---------------------------------------------------------------------------
extern "C" void kernel_launch(void* const* d_in, const int* in_sizes, int n_in,
                              void* d_out, int out_size, void* d_ws,
                              size_t ws_size, hipStream_t stream) {
  const float* x     = (const float*)d_in[0];
  const float* A0    = (const float*)d_in[1];
  const float* A1    = (const float*)d_in[2];
  const float* A2    = (const float*)d_in[3];
  const float* W     = (const float*)d_in[4];
  const float* b     = (const float*)d_in[5];
  const float* gamma = (const float*)d_in[6];
  const float* beta  = (const float*)d_in[7];
  float* out = (float*)d_out;

  char* ws = (char*)d_ws;
  float* stats = (float*)ws;
  const size_t BUF = (size_t)NB * V * CIN;  // 524288 floats
  float* x1_0 = (float*)(ws + 4096);
  float* x2_0 = x1_0 + BUF;
  float* x1_1 = x2_0 + BUF;
  float* x2_1 = x1_1 + BUF;
  float* x1_2 = x2_1 + BUF;
  float* x2_2 = x1_2 + BUF;

  hipMemsetAsync(stats, 0, 2 * COUT * sizeof(float), stream);

  dim3 blk(256);
  // Pipelined chain schedule: hop2(Aj) reads Aj from L3 while A(j+1) streams.
  nconv_mfma_dual_kernel<<<dim3(512), blk, 0, stream>>>(
      A0, x, x1_0, A0, x, x1_0);
  nconv_mfma_dual_kernel<<<dim3(1024), blk, 0, stream>>>(
      A0, x1_0, x2_0, A1, x, x1_1);
  nconv_mfma_dual_kernel<<<dim3(1024), blk, 0, stream>>>(
      A1, x1_1, x2_1, A2, x, x1_2);
  nconv_mfma_dual_kernel<<<dim3(512), blk, 0, stream>>>(
      A2, x1_2, x2_2, A2, x1_2, x2_2);

  conv_bn_stats_kernel<<<dim3(256), blk, 0, stream>>>(
      W, b, x, x1_0, x2_0, x1_1, x2_1, x1_2, x2_2, out, stats);
  bn_apply_kernel<<<dim3(1024), blk, 0, stream>>>(out, stats, gamma, beta);
}